// Round 1
// baseline (150.751 us; speedup 1.0000x reference)
//
#include <hip/hip_runtime.h>

#define B_ 4
#define S_ 4096
#define D_ 64

typedef __attribute__((ext_vector_type(8))) short short8;   // 8 x bf16 (4 VGPRs)
typedef __attribute__((ext_vector_type(4))) float f32x4;    // MFMA C/D
typedef unsigned short u16;

__device__ __forceinline__ u16 f2bf(float x) {
  unsigned u = __float_as_uint(x);
  return (u16)((u + 0x7FFF + ((u >> 16) & 1)) >> 16);  // RNE
}

// ---- pre-pass 1: fp32 -> bf16 (optionally scaled). Used for Q (x 0.125*log2e) and K (x 1).
__global__ void cvt_scale_k(const float* __restrict__ src, u16* __restrict__ dst,
                            float scale, int n8) {
  int t = blockIdx.x * blockDim.x + threadIdx.x;
  if (t >= n8) return;
  const f32x4* s4 = (const f32x4*)src;
  f32x4 a = s4[2 * t], b = s4[2 * t + 1];
  short8 r;
#pragma unroll
  for (int i = 0; i < 4; i++) {
    r[i]     = (short)f2bf(a[i] * scale);
    r[4 + i] = (short)f2bf(b[i] * scale);
  }
  *(short8*)(dst + 8 * (long)t) = r;
}

// ---- pre-pass 2: V -> bf16 in MFMA A-operand (V^T) fragment order.
// Granule layout: [b][c64][nb(4)][js(2)][lane(64)][8 bf16]
// elem i of granule = V[b][c64*64 + js*32 + (lane>>4)*8 + i][nb*16 + (lane&15)]
__global__ void cvt_v_k(const float* __restrict__ v, u16* __restrict__ dst) {
  int t = blockIdx.x * blockDim.x + threadIdx.x;  // 131072 granules
  int lane = t & 63;
  int rest = t >> 6;
  int js = rest & 1;  rest >>= 1;
  int nb = rest & 3;  rest >>= 2;
  int c64 = rest & 63;
  int b = rest >> 6;
  int cc = lane & 15, gg = lane >> 4;
  int row = c64 * 64 + js * 32 + gg * 8;
  int d = nb * 16 + cc;
  const float* src = v + ((long)(b * S_ + row)) * D_ + d;
  short8 r;
#pragma unroll
  for (int i = 0; i < 8; i++) r[i] = (short)f2bf(src[(long)i * D_]);
  *(short8*)(dst + 8 * (long)t) = r;
}

#define MFMA(a, bb, cc) __builtin_amdgcn_mfma_f32_16x16x32_bf16((a), (bb), (cc), 0, 0, 0)

// ---- main: one wave (64 thr) per 16-query tile. S^T = K*Q^T, online softmax (exp2 domain),
//      O^T = V^T * P^T. 1024 blocks, biggest tiles dispatched first.
__global__ __launch_bounds__(64) void attn_k(const u16* __restrict__ wsQ,
                                             const u16* __restrict__ wsK,
                                             const u16* __restrict__ wsV,
                                             float* __restrict__ out) {
  int bid = blockIdx.x;
  int b = bid & 3;
  int tau = 255 - (bid >> 2);   // descending work order
  int q0 = tau << 4;
  int lane = threadIdx.x;
  int c = lane & 15, g = lane >> 4;

  __shared__ float PQ[16][68];  // +4 pad: uniform 8 lanes/bank-group on b128 ops

  const u16* qp = wsQ + ((long)(b * S_ + q0 + c)) * D_ + g * 8;
  short8 qf0 = *(const short8*)qp;          // B-op: Q^T[d=ks*32+g*8+i][q=q0+c], ks=0
  short8 qf1 = *(const short8*)(qp + 32);   // ks=1

  float m = -INFINITY, l = 0.f;
  f32x4 zz = {0.f, 0.f, 0.f, 0.f};
  f32x4 o0 = zz, o1 = zz, o2 = zz, o3 = zz;  // O^T: d = nb*16 + g*4 + reg, q = q0+c

  int nch = (q0 >> 6) + 1;
  for (int ck = 0; ck < nch; ck++) {
    int kb = ck << 6;
    const u16* kp = wsK + ((long)(b * S_ + kb + c)) * D_ + g * 8;
    // A-op K frags: rows kb+jb*16+c, d = ks*32 + g*8
    short8 k00 = *(const short8*)(kp);
    short8 k01 = *(const short8*)(kp + 32);
    short8 k10 = *(const short8*)(kp + 16 * 64);
    short8 k11 = *(const short8*)(kp + 16 * 64 + 32);
    short8 k20 = *(const short8*)(kp + 32 * 64);
    short8 k21 = *(const short8*)(kp + 32 * 64 + 32);
    short8 k30 = *(const short8*)(kp + 48 * 64);
    short8 k31 = *(const short8*)(kp + 48 * 64 + 32);
    // V^T frags (pre-swizzled): granule (((b*64+ck)*4+nb)*2+js)*64+lane
    const u16* vp = wsV + ((long)(((b * 64 + ck) * 8) * 64 + lane)) * 8;
    short8 v00 = *(const short8*)(vp);
    short8 v01 = *(const short8*)(vp + 512);
    short8 v10 = *(const short8*)(vp + 1024);
    short8 v11 = *(const short8*)(vp + 1536);
    short8 v20 = *(const short8*)(vp + 2048);
    short8 v21 = *(const short8*)(vp + 2560);
    short8 v30 = *(const short8*)(vp + 3072);
    short8 v31 = *(const short8*)(vp + 3584);

    // S^T[j][q]: row j = kb + jb*16 + g*4 + reg, col q = q0 + c
    f32x4 s0 = MFMA(k00, qf0, zz); s0 = MFMA(k01, qf1, s0);
    f32x4 s1 = MFMA(k10, qf0, zz); s1 = MFMA(k11, qf1, s1);
    f32x4 s2 = MFMA(k20, qf0, zz); s2 = MFMA(k21, qf1, s2);
    f32x4 s3 = MFMA(k30, qf0, zz); s3 = MFMA(k31, qf1, s3);

    if (ck == nch - 1) {  // causal mask, only diagonal chunk
      int qq = q0 + c;
      int j0 = kb + g * 4;
#pragma unroll
      for (int r2 = 0; r2 < 4; r2++) {
        if (j0 + r2      > qq) s0[r2] = -1e30f;
        if (j0 + 16 + r2 > qq) s1[r2] = -1e30f;
        if (j0 + 32 + r2 > qq) s2[r2] = -1e30f;
        if (j0 + 48 + r2 > qq) s3[r2] = -1e30f;
      }
    }

    // row (per-q) max over the 64 j of this chunk
    float mx = fmaxf(fmaxf(fmaxf(s0[0], s0[1]), fmaxf(s0[2], s0[3])),
                     fmaxf(fmaxf(s1[0], s1[1]), fmaxf(s1[2], s1[3])));
    mx = fmaxf(mx, fmaxf(fmaxf(fmaxf(s2[0], s2[1]), fmaxf(s2[2], s2[3])),
                         fmaxf(fmaxf(s3[0], s3[1]), fmaxf(s3[2], s3[3]))));
    mx = fmaxf(mx, __shfl_xor(mx, 16));
    mx = fmaxf(mx, __shfl_xor(mx, 32));
    float mn = fmaxf(m, mx);
    float al = exp2f(m - mn);

    float sum = 0.f;
#pragma unroll
    for (int r2 = 0; r2 < 4; r2++) {
      s0[r2] = exp2f(s0[r2] - mn); sum += s0[r2];
      s1[r2] = exp2f(s1[r2] - mn); sum += s1[r2];
      s2[r2] = exp2f(s2[r2] - mn); sum += s2[r2];
      s3[r2] = exp2f(s3[r2] - mn); sum += s3[r2];
    }
    sum += __shfl_xor(sum, 16);
    sum += __shfl_xor(sum, 32);
    l = l * al + sum;
    m = mn;
    o0 *= al; o1 *= al; o2 *= al; o3 *= al;

    // P^T -> B-operand via per-wave LDS round trip (no __syncthreads needed: 1 wave)
    *(f32x4*)&PQ[c][0  + g * 4] = s0;
    *(f32x4*)&PQ[c][16 + g * 4] = s1;
    *(f32x4*)&PQ[c][32 + g * 4] = s2;
    *(f32x4*)&PQ[c][48 + g * 4] = s3;
    asm volatile("s_waitcnt lgkmcnt(0)" ::: "memory");
    f32x4 pa0 = *(f32x4*)&PQ[c][g * 8];
    f32x4 pa1 = *(f32x4*)&PQ[c][g * 8 + 4];
    f32x4 pb0 = *(f32x4*)&PQ[c][32 + g * 8];
    f32x4 pb1 = *(f32x4*)&PQ[c][32 + g * 8 + 4];
    asm volatile("" ::: "memory");  // pin order vs next iteration's writes
    short8 p0, p1;  // B-op: P^T[j = js*32 + g*8 + i][q = q0+c]
#pragma unroll
    for (int i = 0; i < 4; i++) {
      p0[i]     = (short)f2bf(pa0[i]);
      p0[4 + i] = (short)f2bf(pa1[i]);
      p1[i]     = (short)f2bf(pb0[i]);
      p1[4 + i] = (short)f2bf(pb1[i]);
    }
    // O^T[d][q] += V^T * P^T
    o0 = MFMA(v00, p0, o0); o0 = MFMA(v01, p1, o0);
    o1 = MFMA(v10, p0, o1); o1 = MFMA(v11, p1, o1);
    o2 = MFMA(v20, p0, o2); o2 = MFMA(v21, p1, o2);
    o3 = MFMA(v30, p0, o3); o3 = MFMA(v31, p1, o3);
  }

  float inv = 1.f / l;
  float* op = out + ((long)(b * S_ + q0 + c)) * D_ + g * 4;
  *(f32x4*)(op)      = o0 * inv;
  *(f32x4*)(op + 16) = o1 * inv;
  *(f32x4*)(op + 32) = o2 * inv;
  *(f32x4*)(op + 48) = o3 * inv;
}

extern "C" void kernel_launch(void* const* d_in, const int* in_sizes, int n_in,
                              void* d_out, int out_size, void* d_ws, size_t ws_size,
                              hipStream_t stream) {
  const float* q = (const float*)d_in[0];
  const float* k = (const float*)d_in[1];
  const float* v = (const float*)d_in[2];
  float* out = (float*)d_out;

  u16* wsQ = (u16*)d_ws;                 // 2 MB
  u16* wsK = wsQ + (long)B_ * S_ * D_;   // 2 MB
  u16* wsV = wsK + (long)B_ * S_ * D_;   // 2 MB  (needs ws_size >= 6 MB)

  const int n8 = B_ * S_ * D_ / 8;  // 131072
  // fold softmax scale (1/sqrt(64)) and log2(e) into Q
  cvt_scale_k<<<512, 256, 0, stream>>>(q, wsQ, 0.18033688011112042f, n8);
  cvt_scale_k<<<512, 256, 0, stream>>>(k, wsK, 1.0f, n8);
  cvt_v_k<<<512, 256, 0, stream>>>(v, wsV);
  attn_k<<<1024, 64, 0, stream>>>(wsQ, wsK, wsV, out);
}

// Round 2
// 110.297 us; speedup vs baseline: 1.3668x; 1.3668x over previous
//
#include <hip/hip_runtime.h>

#define B_ 4
#define S_ 4096
#define D_ 64

typedef __attribute__((ext_vector_type(8))) short short8;   // 8 x bf16 (4 VGPRs)
typedef __attribute__((ext_vector_type(4))) float f32x4;    // MFMA C/D
typedef unsigned short u16;

__device__ __forceinline__ u16 f2bf(float x) {
  unsigned u = __float_as_uint(x);
  return (u16)((u + 0x7FFF + ((u >> 16) & 1)) >> 16);  // RNE
}

// ---- fused pre-pass: Q*scale->bf16, K->bf16, V->bf16 swizzled to MFMA A-op (V^T) order.
// blocks [0,512): Q, [512,1024): K, [1024,1536): V
__global__ __launch_bounds__(256) void cvt_all_k(const float* __restrict__ q,
                                                 const float* __restrict__ k,
                                                 const float* __restrict__ v,
                                                 u16* __restrict__ wsQ,
                                                 u16* __restrict__ wsK,
                                                 u16* __restrict__ wsV) {
  int blk = blockIdx.x;
  if (blk < 1024) {
    const float* src = (blk < 512) ? q : k;
    u16* dst = (blk < 512) ? wsQ : wsK;
    float scale = (blk < 512) ? 0.18033688011112042f : 1.0f;  // 0.125*log2(e) folded into Q
    int t = ((blk & 511) << 8) + threadIdx.x;
    const f32x4* s4 = (const f32x4*)src;
    f32x4 a = s4[2 * t], b = s4[2 * t + 1];
    short8 r;
#pragma unroll
    for (int i = 0; i < 4; i++) {
      r[i]     = (short)f2bf(a[i] * scale);
      r[4 + i] = (short)f2bf(b[i] * scale);
    }
    *(short8*)(dst + 8 * (long)t) = r;
  } else {
    // V granule: [b][c64][nb(4)][js(2)][lane(64)][8 bf16]
    // elem i = V[b][c64*64 + js*32 + (lane>>4)*8 + i][nb*16 + (lane&15)]
    int t = ((blk - 1024) << 8) + threadIdx.x;
    int lane = t & 63;
    int rest = t >> 6;
    int js = rest & 1;  rest >>= 1;
    int nb = rest & 3;  rest >>= 2;
    int c64 = rest & 63;
    int b = rest >> 6;
    int cc = lane & 15, gg = lane >> 4;
    int row = c64 * 64 + js * 32 + gg * 8;
    int d = nb * 16 + cc;
    const float* src = v + ((long)(b * S_ + row)) * D_ + d;
    short8 r;
#pragma unroll
    for (int i = 0; i < 8; i++) r[i] = (short)f2bf(src[(long)i * D_]);
    *(short8*)(wsV + 8 * (long)t) = r;
  }
}

#define MFMA(a, bb, cc) __builtin_amdgcn_mfma_f32_16x16x32_bf16((a), (bb), (cc), 0, 0, 0)

// ---- main: one 4-wave workgroup per 16-query tile. Wave w handles chunks w, w+4, ...
// (64 keys each) with private online-softmax state; LDS merge at the end.
// S^T = K*Q^T (so q sits on the lane axis), O^T = V^T * P^T.
__global__ __launch_bounds__(256) void attn_k(const u16* __restrict__ wsQ,
                                              const u16* __restrict__ wsK,
                                              const u16* __restrict__ wsV,
                                              float* __restrict__ out) {
  int bid = blockIdx.x;
  int b = bid & 3;
  int tau = 255 - (bid >> 2);   // descending work order
  int q0 = tau << 4;
  int tid = threadIdx.x;
  int w = tid >> 6;
  int lane = tid & 63;
  int c = lane & 15, g = lane >> 4;

  __shared__ float sPQ[4][16][68];   // per-wave P^T transpose scratch (+4 pad)
  __shared__ float sO[4][64][17];    // merge: O^T partials [wave][d][q] (+1 pad)
  __shared__ float sML[4][16][2];    // merge: per-wave (m, l) per q

  const u16* qp = wsQ + ((long)(b * S_ + q0 + c)) * D_ + g * 8;
  short8 qf0 = *(const short8*)qp;          // B-op: Q^T[d=ks*32+g*8+i][q=q0+c]
  short8 qf1 = *(const short8*)(qp + 32);

  float m = -INFINITY, l = 0.f;
  f32x4 zz = {0.f, 0.f, 0.f, 0.f};
  f32x4 o0 = zz, o1 = zz, o2 = zz, o3 = zz;  // O^T: d = nb*16 + g*4 + reg, q = q0+c

  int nch = (q0 >> 6) + 1;
  for (int ck = w; ck < nch; ck += 4) {
    int kb = ck << 6;
    const u16* kp = wsK + ((long)(b * S_ + kb + c)) * D_ + g * 8;
    short8 k00 = *(const short8*)(kp);
    short8 k01 = *(const short8*)(kp + 32);
    short8 k10 = *(const short8*)(kp + 16 * 64);
    short8 k11 = *(const short8*)(kp + 16 * 64 + 32);
    short8 k20 = *(const short8*)(kp + 32 * 64);
    short8 k21 = *(const short8*)(kp + 32 * 64 + 32);
    short8 k30 = *(const short8*)(kp + 48 * 64);
    short8 k31 = *(const short8*)(kp + 48 * 64 + 32);
    const u16* vp = wsV + ((long)(((b * 64 + ck) * 8) * 64 + lane)) * 8;
    short8 v00 = *(const short8*)(vp);
    short8 v01 = *(const short8*)(vp + 512);
    short8 v10 = *(const short8*)(vp + 1024);
    short8 v11 = *(const short8*)(vp + 1536);
    short8 v20 = *(const short8*)(vp + 2048);
    short8 v21 = *(const short8*)(vp + 2560);
    short8 v30 = *(const short8*)(vp + 3072);
    short8 v31 = *(const short8*)(vp + 3584);

    // S^T[j][q]: j = kb + jb*16 + g*4 + reg, q = q0 + c
    f32x4 s0 = MFMA(k00, qf0, zz); s0 = MFMA(k01, qf1, s0);
    f32x4 s1 = MFMA(k10, qf0, zz); s1 = MFMA(k11, qf1, s1);
    f32x4 s2 = MFMA(k20, qf0, zz); s2 = MFMA(k21, qf1, s2);
    f32x4 s3 = MFMA(k30, qf0, zz); s3 = MFMA(k31, qf1, s3);

    if (ck == nch - 1) {  // causal mask on diagonal chunk
      int qq = q0 + c;
      int j0 = kb + g * 4;
#pragma unroll
      for (int r2 = 0; r2 < 4; r2++) {
        if (j0 + r2      > qq) s0[r2] = -1e30f;
        if (j0 + 16 + r2 > qq) s1[r2] = -1e30f;
        if (j0 + 32 + r2 > qq) s2[r2] = -1e30f;
        if (j0 + 48 + r2 > qq) s3[r2] = -1e30f;
      }
    }

    float mx = fmaxf(fmaxf(fmaxf(s0[0], s0[1]), fmaxf(s0[2], s0[3])),
                     fmaxf(fmaxf(s1[0], s1[1]), fmaxf(s1[2], s1[3])));
    mx = fmaxf(mx, fmaxf(fmaxf(fmaxf(s2[0], s2[1]), fmaxf(s2[2], s2[3])),
                         fmaxf(fmaxf(s3[0], s3[1]), fmaxf(s3[2], s3[3]))));
    mx = fmaxf(mx, __shfl_xor(mx, 16));
    mx = fmaxf(mx, __shfl_xor(mx, 32));
    float mn = fmaxf(m, mx);
    float al = exp2f(m - mn);

    float sum = 0.f;
#pragma unroll
    for (int r2 = 0; r2 < 4; r2++) {
      s0[r2] = exp2f(s0[r2] - mn); sum += s0[r2];
      s1[r2] = exp2f(s1[r2] - mn); sum += s1[r2];
      s2[r2] = exp2f(s2[r2] - mn); sum += s2[r2];
      s3[r2] = exp2f(s3[r2] - mn); sum += s3[r2];
    }
    sum += __shfl_xor(sum, 16);
    sum += __shfl_xor(sum, 32);
    l = l * al + sum;
    m = mn;
    o0 *= al; o1 *= al; o2 *= al; o3 *= al;

    // P^T (C-layout) -> B-operand via per-wave LDS round trip (no cross-wave sync needed)
    *(f32x4*)&sPQ[w][c][0  + g * 4] = s0;
    *(f32x4*)&sPQ[w][c][16 + g * 4] = s1;
    *(f32x4*)&sPQ[w][c][32 + g * 4] = s2;
    *(f32x4*)&sPQ[w][c][48 + g * 4] = s3;
    asm volatile("s_waitcnt lgkmcnt(0)" ::: "memory");
    f32x4 pa0 = *(f32x4*)&sPQ[w][c][g * 8];
    f32x4 pa1 = *(f32x4*)&sPQ[w][c][g * 8 + 4];
    f32x4 pb0 = *(f32x4*)&sPQ[w][c][32 + g * 8];
    f32x4 pb1 = *(f32x4*)&sPQ[w][c][32 + g * 8 + 4];
    asm volatile("" ::: "memory");  // pin order vs next iteration's writes
    short8 p0, p1;  // B-op: P^T[j = js*32 + g*8 + i][q]
#pragma unroll
    for (int i = 0; i < 4; i++) {
      p0[i]     = (short)f2bf(pa0[i]);
      p0[4 + i] = (short)f2bf(pa1[i]);
      p1[i]     = (short)f2bf(pb0[i]);
      p1[4 + i] = (short)f2bf(pb1[i]);
    }
    o0 = MFMA(v00, p0, o0); o0 = MFMA(v01, p1, o0);
    o1 = MFMA(v10, p0, o1); o1 = MFMA(v11, p1, o1);
    o2 = MFMA(v20, p0, o2); o2 = MFMA(v21, p1, o2);
    o3 = MFMA(v30, p0, o3); o3 = MFMA(v31, p1, o3);
  }

  // ---- stash partials, merge across the 4 waves in LDS
  if (g == 0) { sML[w][c][0] = m; sML[w][c][1] = l; }
#pragma unroll
  for (int r = 0; r < 4; r++) {
    sO[w][ 0 + g * 4 + r][c] = o0[r];
    sO[w][16 + g * 4 + r][c] = o1[r];
    sO[w][32 + g * 4 + r][c] = o2[r];
    sO[w][48 + g * 4 + r][c] = o3[r];
  }
  __syncthreads();

  // thread -> (q, 4 consecutive d); lanes cover a full 16-d row stripe for coalesced stores
  int q = tid >> 4;
  int d4 = tid & 15;
  float mg = fmaxf(fmaxf(sML[0][q][0], sML[1][q][0]), fmaxf(sML[2][q][0], sML[3][q][0]));
  float lg = 0.f;
  f32x4 acc = {0.f, 0.f, 0.f, 0.f};
#pragma unroll
  for (int w2 = 0; w2 < 4; w2++) {
    float a = exp2f(sML[w2][q][0] - mg);
    lg += a * sML[w2][q][1];
#pragma unroll
    for (int i = 0; i < 4; i++) acc[i] += a * sO[w2][d4 * 4 + i][q];
  }
  float inv = 1.f / lg;
  float* op = out + ((long)(b * S_ + q0 + q)) * D_ + d4 * 4;
  *(f32x4*)op = acc * inv;
}

extern "C" void kernel_launch(void* const* d_in, const int* in_sizes, int n_in,
                              void* d_out, int out_size, void* d_ws, size_t ws_size,
                              hipStream_t stream) {
  const float* q = (const float*)d_in[0];
  const float* k = (const float*)d_in[1];
  const float* v = (const float*)d_in[2];
  float* out = (float*)d_out;

  u16* wsQ = (u16*)d_ws;                 // 2 MB
  u16* wsK = wsQ + (long)B_ * S_ * D_;   // 2 MB
  u16* wsV = wsK + (long)B_ * S_ * D_;   // 2 MB  (needs ws_size >= 6 MB)

  cvt_all_k<<<1536, 256, 0, stream>>>(q, k, v, wsQ, wsK, wsV);
  attn_k<<<1024, 256, 0, stream>>>(wsQ, wsK, wsV, out);
}

// Round 3
// 109.821 us; speedup vs baseline: 1.3727x; 1.0043x over previous
//
#include <hip/hip_runtime.h>

#define B_ 4
#define S_ 4096
#define D_ 64

typedef __attribute__((ext_vector_type(8))) short short8;   // 8 x bf16 (4 VGPRs)
typedef __attribute__((ext_vector_type(4))) float f32x4;    // MFMA C/D
typedef __attribute__((ext_vector_type(4))) int int4v;
typedef unsigned short u16;

// pack two fp32 -> two bf16 (round-half-up) in one v_perm_b32
__device__ __forceinline__ int pack_bf2(float a, float b) {
  unsigned ua = __float_as_uint(a) + 0x8000u;
  unsigned ub = __float_as_uint(b) + 0x8000u;
  return __builtin_amdgcn_perm(ub, ua, 0x07060302);  // D = {lo: ua[31:16], hi: ub[31:16]}
}

// ---- fused pre-pass: Q*scale->bf16, K->bf16, V->bf16 swizzled to MFMA A-op (V^T) order.
// blocks [0,512): Q, [512,1024): K, [1024,1536): V
__global__ __launch_bounds__(256) void cvt_all_k(const float* __restrict__ q,
                                                 const float* __restrict__ k,
                                                 const float* __restrict__ v,
                                                 u16* __restrict__ wsQ,
                                                 u16* __restrict__ wsK,
                                                 u16* __restrict__ wsV) {
  int blk = blockIdx.x;
  if (blk < 1024) {
    const float* src = (blk < 512) ? q : k;
    u16* dst = (blk < 512) ? wsQ : wsK;
    float scale = (blk < 512) ? 0.18033688011112042f : 1.0f;  // 0.125*log2(e) folded into Q
    int t = ((blk & 511) << 8) + threadIdx.x;
    const f32x4* s4 = (const f32x4*)src;
    f32x4 a = s4[2 * t], b = s4[2 * t + 1];
    int4v r;
    r[0] = pack_bf2(a[0] * scale, a[1] * scale);
    r[1] = pack_bf2(a[2] * scale, a[3] * scale);
    r[2] = pack_bf2(b[0] * scale, b[1] * scale);
    r[3] = pack_bf2(b[2] * scale, b[3] * scale);
    *(int4v*)(dst + 8 * (long)t) = r;
  } else {
    // V granule: [b][c64][nb(4)][js(2)][lane(64)][8 bf16]
    // elem i = V[b][c64*64 + js*32 + (lane>>4)*8 + i][nb*16 + (lane&15)]
    int t = ((blk - 1024) << 8) + threadIdx.x;
    int lane = t & 63;
    int rest = t >> 6;
    int js = rest & 1;  rest >>= 1;
    int nb = rest & 3;  rest >>= 2;
    int c64 = rest & 63;
    int b = rest >> 6;
    int cc = lane & 15, gg = lane >> 4;
    int row = c64 * 64 + js * 32 + gg * 8;
    int d = nb * 16 + cc;
    const float* src = v + ((long)(b * S_ + row)) * D_ + d;
    float e[8];
#pragma unroll
    for (int i = 0; i < 8; i++) e[i] = src[(long)i * D_];
    int4v r;
    r[0] = pack_bf2(e[0], e[1]);
    r[1] = pack_bf2(e[2], e[3]);
    r[2] = pack_bf2(e[4], e[5]);
    r[3] = pack_bf2(e[6], e[7]);
    *(int4v*)(wsV + 8 * (long)t) = r;
  }
}

#define MFMA(a, bb, cc) __builtin_amdgcn_mfma_f32_16x16x32_bf16((a), (bb), (cc), 0, 0, 0)

// ---- main: one 4-wave workgroup per 16-query tile. Wave w handles chunks w, w+4, ...
// (64 keys each) with private online-softmax state; LDS merge at the end.
// S^T = K*Q^T (q on lane axis), O^T = V^T * P^T.
// LDS: per-wave 16x68 fp32 buffer reused for (a) P^T transpose in-loop, (b) O partials
// (q-major) for the merge. Union keeps LDS at 17.9 KB -> 8 blocks/CU resident.
__global__ __launch_bounds__(256) void attn_k(const u16* __restrict__ wsQ,
                                              const u16* __restrict__ wsK,
                                              const u16* __restrict__ wsV,
                                              float* __restrict__ out) {
  int bid = blockIdx.x;
  int b = bid & 3;
  int tau = 255 - (bid >> 2);   // descending work order
  int q0 = tau << 4;
  int tid = threadIdx.x;
  int w = tid >> 6;
  int lane = tid & 63;
  int c = lane & 15, g = lane >> 4;

  __shared__ float sBuf[4][16][68];  // per-wave scratch, row stride 68 (+4 pad)
  __shared__ float sML[4][16][2];    // per-wave (m, l) per q

  float* PQ = &sBuf[w][0][0];        // this wave's scratch, stride 68

  const u16* qp = wsQ + ((long)(b * S_ + q0 + c)) * D_ + g * 8;
  short8 qf0 = *(const short8*)qp;          // B-op: Q^T[d=ks*32+g*8+i][q=q0+c]
  short8 qf1 = *(const short8*)(qp + 32);

  float m = -INFINITY, l = 0.f;
  f32x4 zz = {0.f, 0.f, 0.f, 0.f};
  f32x4 o0 = zz, o1 = zz, o2 = zz, o3 = zz;  // O^T: d = nb*16 + g*4 + reg, q = q0+c

  int nch = (q0 >> 6) + 1;
  for (int ck = w; ck < nch; ck += 4) {
    int kb = ck << 6;
    const u16* kp = wsK + ((long)(b * S_ + kb + c)) * D_ + g * 8;
    short8 k00 = *(const short8*)(kp);
    short8 k01 = *(const short8*)(kp + 32);
    short8 k10 = *(const short8*)(kp + 16 * 64);
    short8 k11 = *(const short8*)(kp + 16 * 64 + 32);
    short8 k20 = *(const short8*)(kp + 32 * 64);
    short8 k21 = *(const short8*)(kp + 32 * 64 + 32);
    short8 k30 = *(const short8*)(kp + 48 * 64);
    short8 k31 = *(const short8*)(kp + 48 * 64 + 32);
    const u16* vp = wsV + ((long)(((b * 64 + ck) * 8) * 64 + lane)) * 8;
    short8 v00 = *(const short8*)(vp);
    short8 v01 = *(const short8*)(vp + 512);
    short8 v10 = *(const short8*)(vp + 1024);
    short8 v11 = *(const short8*)(vp + 1536);
    short8 v20 = *(const short8*)(vp + 2048);
    short8 v21 = *(const short8*)(vp + 2560);
    short8 v30 = *(const short8*)(vp + 3072);
    short8 v31 = *(const short8*)(vp + 3584);

    // S^T[j][q]: j = kb + jb*16 + g*4 + reg, q = q0 + c
    f32x4 s0 = MFMA(k00, qf0, zz); s0 = MFMA(k01, qf1, s0);
    f32x4 s1 = MFMA(k10, qf0, zz); s1 = MFMA(k11, qf1, s1);
    f32x4 s2 = MFMA(k20, qf0, zz); s2 = MFMA(k21, qf1, s2);
    f32x4 s3 = MFMA(k30, qf0, zz); s3 = MFMA(k31, qf1, s3);

    if (ck == nch - 1) {  // causal mask on diagonal chunk
      int qq = q0 + c;
      int j0 = kb + g * 4;
#pragma unroll
      for (int r2 = 0; r2 < 4; r2++) {
        if (j0 + r2      > qq) s0[r2] = -1e30f;
        if (j0 + 16 + r2 > qq) s1[r2] = -1e30f;
        if (j0 + 32 + r2 > qq) s2[r2] = -1e30f;
        if (j0 + 48 + r2 > qq) s3[r2] = -1e30f;
      }
    }

    float mx = fmaxf(fmaxf(fmaxf(s0[0], s0[1]), fmaxf(s0[2], s0[3])),
                     fmaxf(fmaxf(s1[0], s1[1]), fmaxf(s1[2], s1[3])));
    mx = fmaxf(mx, fmaxf(fmaxf(fmaxf(s2[0], s2[1]), fmaxf(s2[2], s2[3])),
                         fmaxf(fmaxf(s3[0], s3[1]), fmaxf(s3[2], s3[3]))));
    mx = fmaxf(mx, __shfl_xor(mx, 16));
    mx = fmaxf(mx, __shfl_xor(mx, 32));
    float mn = fmaxf(m, mx);
    float al = exp2f(m - mn);

    float sum = 0.f;
#pragma unroll
    for (int r2 = 0; r2 < 4; r2++) {
      s0[r2] = exp2f(s0[r2] - mn); sum += s0[r2];
      s1[r2] = exp2f(s1[r2] - mn); sum += s1[r2];
      s2[r2] = exp2f(s2[r2] - mn); sum += s2[r2];
      s3[r2] = exp2f(s3[r2] - mn); sum += s3[r2];
    }
    sum += __shfl_xor(sum, 16);
    sum += __shfl_xor(sum, 32);
    l = l * al + sum;
    m = mn;
    o0 *= al; o1 *= al; o2 *= al; o3 *= al;

    // P^T (C-layout) -> B-operand via per-wave LDS round trip (no cross-wave sync needed)
    *(f32x4*)&PQ[c * 68 + 0  + g * 4] = s0;
    *(f32x4*)&PQ[c * 68 + 16 + g * 4] = s1;
    *(f32x4*)&PQ[c * 68 + 32 + g * 4] = s2;
    *(f32x4*)&PQ[c * 68 + 48 + g * 4] = s3;
    asm volatile("s_waitcnt lgkmcnt(0)" ::: "memory");
    f32x4 pa0 = *(f32x4*)&PQ[c * 68 + g * 8];
    f32x4 pa1 = *(f32x4*)&PQ[c * 68 + g * 8 + 4];
    f32x4 pb0 = *(f32x4*)&PQ[c * 68 + 32 + g * 8];
    f32x4 pb1 = *(f32x4*)&PQ[c * 68 + 32 + g * 8 + 4];
    asm volatile("" ::: "memory");  // pin order vs next iteration's writes
    int4v pi0, pi1;  // B-op: P^T[j = js*32 + g*8 + i][q]
    pi0[0] = pack_bf2(pa0[0], pa0[1]);
    pi0[1] = pack_bf2(pa0[2], pa0[3]);
    pi0[2] = pack_bf2(pa1[0], pa1[1]);
    pi0[3] = pack_bf2(pa1[2], pa1[3]);
    pi1[0] = pack_bf2(pb0[0], pb0[1]);
    pi1[1] = pack_bf2(pb0[2], pb0[3]);
    pi1[2] = pack_bf2(pb1[0], pb1[1]);
    pi1[3] = pack_bf2(pb1[2], pb1[3]);
    short8 p0 = __builtin_bit_cast(short8, pi0);
    short8 p1 = __builtin_bit_cast(short8, pi1);
    o0 = MFMA(v00, p0, o0); o0 = MFMA(v01, p1, o0);
    o1 = MFMA(v10, p0, o1); o1 = MFMA(v11, p1, o1);
    o2 = MFMA(v20, p0, o2); o2 = MFMA(v21, p1, o2);
    o3 = MFMA(v30, p0, o3); o3 = MFMA(v31, p1, o3);
  }

  // ---- stash partials (q-major: sBuf[w][q][d]) and merge across the 4 waves
  if (g == 0) { sML[w][c][0] = m; sML[w][c][1] = l; }
  *(f32x4*)&PQ[c * 68 + 0  + g * 4] = o0;   // d = 0..15
  *(f32x4*)&PQ[c * 68 + 16 + g * 4] = o1;   // d = 16..31
  *(f32x4*)&PQ[c * 68 + 32 + g * 4] = o2;
  *(f32x4*)&PQ[c * 68 + 48 + g * 4] = o3;
  __syncthreads();

  // thread -> (q = tid>>4, 4 consecutive d = (tid&15)*4); coalesced f32x4 stores
  int q = tid >> 4;
  int d4 = tid & 15;
  float mg = fmaxf(fmaxf(sML[0][q][0], sML[1][q][0]), fmaxf(sML[2][q][0], sML[3][q][0]));
  float lg = 0.f;
  f32x4 acc = {0.f, 0.f, 0.f, 0.f};
#pragma unroll
  for (int w2 = 0; w2 < 4; w2++) {
    float a = exp2f(sML[w2][q][0] - mg);
    lg += a * sML[w2][q][1];
    f32x4 part = *(f32x4*)&sBuf[w2][q][d4 * 4];
#pragma unroll
    for (int i = 0; i < 4; i++) acc[i] += a * part[i];
  }
  float inv = 1.f / lg;
  float* op = out + ((long)(b * S_ + q0 + q)) * D_ + d4 * 4;
  *(f32x4*)op = acc * inv;
}

extern "C" void kernel_launch(void* const* d_in, const int* in_sizes, int n_in,
                              void* d_out, int out_size, void* d_ws, size_t ws_size,
                              hipStream_t stream) {
  const float* q = (const float*)d_in[0];
  const float* k = (const float*)d_in[1];
  const float* v = (const float*)d_in[2];
  float* out = (float*)d_out;

  u16* wsQ = (u16*)d_ws;                 // 2 MB
  u16* wsK = wsQ + (long)B_ * S_ * D_;   // 2 MB
  u16* wsV = wsK + (long)B_ * S_ * D_;   // 2 MB  (needs ws_size >= 6 MB)

  cvt_all_k<<<1536, 256, 0, stream>>>(q, k, v, wsQ, wsK, wsV);
  attn_k<<<1024, 256, 0, stream>>>(wsQ, wsK, wsV, out);
}

// Round 4
// 100.872 us; speedup vs baseline: 1.4945x; 1.0887x over previous
//
#include <hip/hip_runtime.h>

#define B_ 4
#define S_ 4096
#define D_ 64
#define SLOTF 544  // floats per partial slot: m[16], l[16], O as 1024 bf16 (=512 words)

typedef __attribute__((ext_vector_type(8))) short short8;   // 8 x bf16 (4 VGPRs)
typedef __attribute__((ext_vector_type(4))) float f32x4;    // MFMA C/D
typedef __attribute__((ext_vector_type(4))) int int4v;
typedef __attribute__((ext_vector_type(2))) unsigned uint2v;
typedef unsigned short u16;

// pack two fp32 -> two bf16 (round-half-up) in one v_perm_b32
__device__ __forceinline__ unsigned pack_bf2(float a, float b) {
  unsigned ua = __float_as_uint(a) + 0x8000u;
  unsigned ub = __float_as_uint(b) + 0x8000u;
  return __builtin_amdgcn_perm(ub, ua, 0x07060302);  // {lo: ua[31:16], hi: ub[31:16]}
}

// ---- fused pre-pass: Q*scale->bf16, K->bf16, V->bf16 swizzled to MFMA A-op (V^T) order.
__global__ __launch_bounds__(256) void cvt_all_k(const float* __restrict__ q,
                                                 const float* __restrict__ k,
                                                 const float* __restrict__ v,
                                                 u16* __restrict__ wsQ,
                                                 u16* __restrict__ wsK,
                                                 u16* __restrict__ wsV) {
  int blk = blockIdx.x;
  if (blk < 1024) {
    const float* src = (blk < 512) ? q : k;
    u16* dst = (blk < 512) ? wsQ : wsK;
    float scale = (blk < 512) ? 0.18033688011112042f : 1.0f;  // 0.125*log2(e) into Q
    int t = ((blk & 511) << 8) + threadIdx.x;
    const f32x4* s4 = (const f32x4*)src;
    f32x4 a = s4[2 * t], b = s4[2 * t + 1];
    int4v r;
    r[0] = (int)pack_bf2(a[0] * scale, a[1] * scale);
    r[1] = (int)pack_bf2(a[2] * scale, a[3] * scale);
    r[2] = (int)pack_bf2(b[0] * scale, b[1] * scale);
    r[3] = (int)pack_bf2(b[2] * scale, b[3] * scale);
    *(int4v*)(dst + 8 * (long)t) = r;
  } else {
    // V granule: [b][c64][nb(4)][js(2)][lane(64)][8 bf16]
    // elem i = V[b][c64*64 + js*32 + (lane>>4)*8 + i][nb*16 + (lane&15)]
    int t = ((blk - 1024) << 8) + threadIdx.x;
    int lane = t & 63;
    int rest = t >> 6;
    int js = rest & 1;  rest >>= 1;
    int nb = rest & 3;  rest >>= 2;
    int c64 = rest & 63;
    int b = rest >> 6;
    int cc = lane & 15, gg = lane >> 4;
    int row = c64 * 64 + js * 32 + gg * 8;
    int d = nb * 16 + cc;
    const float* src = v + ((long)(b * S_ + row)) * D_ + d;
    float e[8];
#pragma unroll
    for (int i = 0; i < 8; i++) e[i] = src[(long)i * D_];
    int4v r;
    r[0] = (int)pack_bf2(e[0], e[1]);
    r[1] = (int)pack_bf2(e[2], e[3]);
    r[2] = (int)pack_bf2(e[4], e[5]);
    r[3] = (int)pack_bf2(e[6], e[7]);
    *(int4v*)(wsV + 8 * (long)t) = r;
  }
}

#define MFMA(a, bb, cc) __builtin_amdgcn_mfma_f32_16x16x32_bf16((a), (bb), (cc), 0, 0, 0)

// ---- main: block = (quad g, batch b, ksq). 4 waves, wave handles chunks ks=4*ksq+w,
// ks+16, ... for ALL 4 tiles of the quad (64 queries) -> each 16KB K/V chunk load
// serves 64 q (L2 traffic /4). Partials (m,l,O) per (tile,ksq) go to global ws.
__global__ __launch_bounds__(256, 2) void attn_k(const u16* __restrict__ wsQ,
                                                 const u16* __restrict__ wsK,
                                                 const u16* __restrict__ wsV,
                                                 float* __restrict__ part) {
  int bid = blockIdx.x;
  int g   = 63 - (bid >> 4);    // quad index, descending work order
  int b   = (bid >> 2) & 3;
  int ksq = bid & 3;
  int tid = threadIdx.x;
  int w = tid >> 6, lane = tid & 63, c = lane & 15, g4 = lane >> 4;
  int ks = ksq * 4 + w;

  __shared__ float sBuf[4][16][68];      // merge scratch (q-major O partials)
  __shared__ float sP[4][2][16][36];     // per-wave packed-P scratch, x2 regions
  __shared__ float sML[4][16][2];

  short8 qf0[4], qf1[4];
#pragma unroll
  for (int t = 0; t < 4; t++) {
    const u16* qp = wsQ + ((long)(b * S_ + g * 64 + t * 16 + c)) * D_ + g4 * 8;
    qf0[t] = *(const short8*)qp;
    qf1[t] = *(const short8*)(qp + 32);
  }
  f32x4 zz = {0.f, 0.f, 0.f, 0.f};
  float m[4], l[4];
  f32x4 o[4][4];
#pragma unroll
  for (int t = 0; t < 4; t++) {
    m[t] = -INFINITY; l[t] = 0.f;
#pragma unroll
    for (int n = 0; n < 4; n++) o[t][n] = zz;
  }

  for (int ck = ks; ck <= g; ck += 16) {
    const u16* kp = wsK + ((long)(b * S_ + ck * 64 + c)) * D_ + g4 * 8;
    short8 kf[8];
#pragma unroll
    for (int jb = 0; jb < 4; jb++) {
      kf[jb * 2]     = *(const short8*)(kp + jb * 1024);
      kf[jb * 2 + 1] = *(const short8*)(kp + jb * 1024 + 32);
    }
    const u16* vp = wsV + ((long)((b * 64 + ck) * 8 * 64 + lane)) * 8;
    short8 vf[8];
#pragma unroll
    for (int i = 0; i < 8; i++) vf[i] = *(const short8*)(vp + 512 * i);

#pragma unroll
    for (int t = 0; t < 4; t++) {
      // S^T[j][q]: j = 64*ck + jb*16 + g4*4 + r, q = 64g + 16t + c
      f32x4 s0 = MFMA(kf[0], qf0[t], zz); s0 = MFMA(kf[1], qf1[t], s0);
      f32x4 s1 = MFMA(kf[2], qf0[t], zz); s1 = MFMA(kf[3], qf1[t], s1);
      f32x4 s2 = MFMA(kf[4], qf0[t], zz); s2 = MFMA(kf[5], qf1[t], s2);
      f32x4 s3 = MFMA(kf[6], qf0[t], zz); s3 = MFMA(kf[7], qf1[t], s3);

      if (ck == g) {  // diagonal chunk: causal mask (local coords)
        int qq = t * 16 + c;
        int j0 = g4 * 4;
#pragma unroll
        for (int r2 = 0; r2 < 4; r2++) {
          if (j0 + r2      > qq) s0[r2] = -1e30f;
          if (j0 + 16 + r2 > qq) s1[r2] = -1e30f;
          if (j0 + 32 + r2 > qq) s2[r2] = -1e30f;
          if (j0 + 48 + r2 > qq) s3[r2] = -1e30f;
        }
      }

      float mx = fmaxf(fmaxf(fmaxf(s0[0], s0[1]), fmaxf(s0[2], s0[3])),
                       fmaxf(fmaxf(s1[0], s1[1]), fmaxf(s1[2], s1[3])));
      mx = fmaxf(mx, fmaxf(fmaxf(fmaxf(s2[0], s2[1]), fmaxf(s2[2], s2[3])),
                           fmaxf(fmaxf(s3[0], s3[1]), fmaxf(s3[2], s3[3]))));
      mx = fmaxf(mx, __shfl_xor(mx, 16));
      mx = fmaxf(mx, __shfl_xor(mx, 32));
      float mn = fmaxf(m[t], mx);
      float al = exp2f(m[t] - mn);

      float sum = 0.f;
#pragma unroll
      for (int r2 = 0; r2 < 4; r2++) {
        s0[r2] = exp2f(s0[r2] - mn); sum += s0[r2];
        s1[r2] = exp2f(s1[r2] - mn); sum += s1[r2];
        s2[r2] = exp2f(s2[r2] - mn); sum += s2[r2];
        s3[r2] = exp2f(s3[r2] - mn); sum += s3[r2];
      }
      sum += __shfl_xor(sum, 16);
      sum += __shfl_xor(sum, 32);
      l[t] = l[t] * al + sum;
      m[t] = mn;
#pragma unroll
      for (int n = 0; n < 4; n++) o[t][n] *= al;

      // P^T -> B-operand: pack bf16 pairs (rows 2w,2w+1 share a word), per-wave LDS RT
      float* P = &sP[w][t & 1][0][0];
      uint2v w0 = {pack_bf2(s0[0], s0[1]), pack_bf2(s0[2], s0[3])};
      uint2v w1 = {pack_bf2(s1[0], s1[1]), pack_bf2(s1[2], s1[3])};
      uint2v w2 = {pack_bf2(s2[0], s2[1]), pack_bf2(s2[2], s2[3])};
      uint2v w3 = {pack_bf2(s3[0], s3[1]), pack_bf2(s3[2], s3[3])};
      *(uint2v*)&P[c * 36 + 2 * g4]      = w0;   // words jb*8 + 2*g4
      *(uint2v*)&P[c * 36 + 2 * g4 + 8]  = w1;
      *(uint2v*)&P[c * 36 + 2 * g4 + 16] = w2;
      *(uint2v*)&P[c * 36 + 2 * g4 + 24] = w3;
      asm volatile("s_waitcnt lgkmcnt(0)" ::: "memory");
      short8 p0 = *(const short8*)&P[c * 36 + 4 * g4];       // rows 8g4..8g4+7
      short8 p1 = *(const short8*)&P[c * 36 + 16 + 4 * g4];  // rows 32+8g4..
      asm volatile("" ::: "memory");
      o[t][0] = MFMA(vf[0], p0, o[t][0]); o[t][0] = MFMA(vf[1], p1, o[t][0]);
      o[t][1] = MFMA(vf[2], p0, o[t][1]); o[t][1] = MFMA(vf[3], p1, o[t][1]);
      o[t][2] = MFMA(vf[4], p0, o[t][2]); o[t][2] = MFMA(vf[5], p1, o[t][2]);
      o[t][3] = MFMA(vf[6], p0, o[t][3]); o[t][3] = MFMA(vf[7], p1, o[t][3]);
    }
  }

  // ---- per tile: in-block merge of 4 ks-waves, write partial slot (b, tau, ksq)
  for (int t = 0; t < 4; t++) {
    if (g4 == 0) { sML[w][c][0] = m[t]; sML[w][c][1] = l[t]; }
#pragma unroll
    for (int n = 0; n < 4; n++)
      *(f32x4*)&sBuf[w][c][n * 16 + g4 * 4] = o[t][n];  // q-major
    __syncthreads();

    int q = tid >> 4, d4 = tid & 15;
    float M = fmaxf(fmaxf(sML[0][q][0], sML[1][q][0]),
                    fmaxf(sML[2][q][0], sML[3][q][0]));
    float L = 0.f;
    f32x4 acc = {0.f, 0.f, 0.f, 0.f};
#pragma unroll
    for (int w2 = 0; w2 < 4; w2++) {
      float mw = sML[w2][q][0];
      float a = (mw > -INFINITY) ? exp2f(mw - M) : 0.f;
      L += a * sML[w2][q][1];
      f32x4 pv = *(f32x4*)&sBuf[w2][q][d4 * 4];
#pragma unroll
      for (int i = 0; i < 4; i++) acc[i] += a * pv[i];
    }
    float* sp = part + ((long)((b * 256 + g * 4 + t) * 4 + ksq)) * SLOTF;
    if (d4 == 0) { sp[q] = M; sp[16 + q] = L; }
    uint2v pw = {pack_bf2(acc[0], acc[1]), pack_bf2(acc[2], acc[3])};
    *(uint2v*)((u16*)(sp + 32) + q * 64 + d4 * 4) = pw;
    __syncthreads();
  }
}

// ---- merge the 4 ksq partials per tile, normalize, write fp32 output
__global__ __launch_bounds__(256) void merge_k(const float* __restrict__ part,
                                               float* __restrict__ out) {
  int bid = blockIdx.x;            // b*256 + tau
  int b = bid >> 8, tau = bid & 255;
  int tid = threadIdx.x, q = tid >> 4, d4 = tid & 15;
  const float* base = part + (long)bid * (4 * SLOTF);
  float M = -INFINITY;
#pragma unroll
  for (int s = 0; s < 4; s++) M = fmaxf(M, base[s * SLOTF + q]);
  float L = 0.f;
  f32x4 acc = {0.f, 0.f, 0.f, 0.f};
#pragma unroll
  for (int s = 0; s < 4; s++) {
    float ms = base[s * SLOTF + q];
    float a = (ms > -INFINITY) ? exp2f(ms - M) : 0.f;
    L += a * base[s * SLOTF + 16 + q];
    const u16* Op = (const u16*)(base + s * SLOTF + 32) + q * 64 + d4 * 4;
    uint2v pw = *(const uint2v*)Op;
    acc[0] += a * __uint_as_float(pw[0] << 16);
    acc[1] += a * __uint_as_float(pw[0] & 0xffff0000u);
    acc[2] += a * __uint_as_float(pw[1] << 16);
    acc[3] += a * __uint_as_float(pw[1] & 0xffff0000u);
  }
  float inv = 1.f / L;
  f32x4 r;
#pragma unroll
  for (int i = 0; i < 4; i++) r[i] = acc[i] * inv;
  *(f32x4*)(out + ((long)(b * S_ + tau * 16 + q)) * D_ + d4 * 4) = r;
}

extern "C" void kernel_launch(void* const* d_in, const int* in_sizes, int n_in,
                              void* d_out, int out_size, void* d_ws, size_t ws_size,
                              hipStream_t stream) {
  const float* q = (const float*)d_in[0];
  const float* k = (const float*)d_in[1];
  const float* v = (const float*)d_in[2];
  float* out = (float*)d_out;

  u16* wsQ = (u16*)d_ws;                 // 2 MB
  u16* wsK = wsQ + (long)B_ * S_ * D_;   // 2 MB
  u16* wsV = wsK + (long)B_ * S_ * D_;   // 2 MB
  float* part = (float*)(wsV + (long)B_ * S_ * D_);  // 1024*4*SLOTF floats = 8.9 MB

  cvt_all_k<<<1536, 256, 0, stream>>>(q, k, v, wsQ, wsK, wsV);
  attn_k<<<1024, 256, 0, stream>>>(wsQ, wsK, wsV, part);
  merge_k<<<1024, 256, 0, stream>>>(part, out);
}